// Round 1
// baseline (1394.081 us; speedup 1.0000x reference)
//
#include <hip/hip_runtime.h>
#include <math.h>

// Problem constants
constexpr int kB = 4, kG = 2048, kD = 256, kH = 8, kHD = 32, kL = 4, kFFN = 1024;
constexpr int kBG = kB * kG;                  // 8192 tokens
constexpr int kCHUNK = 64;                    // linear-attn chunk length
constexpr int kNC = kG / kCHUNK;              // 32 chunks per sequence
constexpr int kSUMSZ = kHD * kHD + kHD;       // 1056 floats per chunk-state

// ---------------------------------------------------------------------------
// h[b,g,d] = gene_emb[g,d] + ree(x[b,g], d)
__global__ void embed_kernel(const float* __restrict__ x,
                             const float* __restrict__ ge,
                             float* __restrict__ h) {
  int idx = blockIdx.x * 256 + threadIdx.x;   // over kB*kG*kD = 2^21
  int d = idx & (kD - 1);
  int g = (idx >> 8) & (kG - 1);
  int b = idx >> 19;                          // / (kG*kD) = 2^19
  float xv = x[b * kG + g];
  int i = d & 127;
  // inv_freq[i] = 100^(-i/128) = exp(-i*ln(100)/128)
  float inv = expf(-(float)i * (4.6051701859880914f / 128.0f));
  float f = xv * inv;
  float r = (d < 128) ? sinf(f) : cosf(f);
  if (xv == -10.0f) r = 0.0f;
  h[idx] = ge[g * kD + d] + r;
}

// ---------------------------------------------------------------------------
// Row LayerNorm over D=256, block = 256 threads (one per element)
__global__ void ln_kernel(const float* __restrict__ h,
                          const float* __restrict__ gamma,
                          const float* __restrict__ beta,
                          float* __restrict__ z) {
  int row = blockIdx.x;
  int t = threadIdx.x;
  float v = h[(size_t)row * kD + t];
  float s = v, sq = v * v;
#pragma unroll
  for (int o = 32; o > 0; o >>= 1) {
    s += __shfl_down(s, o);
    sq += __shfl_down(sq, o);
  }
  __shared__ float s1[4], s2[4];
  if ((t & 63) == 0) { s1[t >> 6] = s; s2[t >> 6] = sq; }
  __syncthreads();
  float mu = (s1[0] + s1[1] + s1[2] + s1[3]) * (1.0f / kD);
  float var = (s2[0] + s2[1] + s2[2] + s2[3]) * (1.0f / kD) - mu * mu;
  float r = rsqrtf(var + 1e-5f);
  z[(size_t)row * kD + t] = (v - mu) * r * gamma[t] + beta[t];
}

// ---------------------------------------------------------------------------
// C[M,N] = epi(A[M,K] @ W[K,N] + bias[N])
// EPI: 0=plain, 1=square, 2=exact gelu, 3=residual add into C
// BM=128, BN=64, BK=16, 256 threads, 8x4 micro-tile per thread.
template <int EPI>
__global__ __launch_bounds__(256) void gemm_kernel(
    const float* __restrict__ A, const float* __restrict__ W,
    const float* __restrict__ bias, float* __restrict__ C,
    int M, int N, int K) {
  constexpr int BM = 128, BN = 64, BK = 16;
  __shared__ float As[BK][BM + 4];   // +4 pad: float4-aligned, bank-spread
  __shared__ float Bs[BK][BN + 4];
  const int t = threadIdx.x;
  const int bm = blockIdx.y * BM;
  const int bn = blockIdx.x * BN;
  const int tx = t & 15, ty = t >> 4;
  float acc[8][4];
#pragma unroll
  for (int i = 0; i < 8; i++)
#pragma unroll
    for (int j = 0; j < 4; j++) acc[i][j] = 0.0f;

  const int am = t >> 2;            // 0..63  (A row within tile, +64 for 2nd)
  const int ak = (t & 3) * 4;       // 0,4,8,12 (k-offset of float4)
  const int bk = t >> 4;            // 0..15  (W row within tile)
  const int bn4 = (t & 15) * 4;     // n-offset of float4
  const float* Ap0 = A + (size_t)(bm + am) * K + ak;
  const float* Ap1 = A + (size_t)(bm + am + 64) * K + ak;
  const float* Wp  = W + (size_t)bk * N + bn + bn4;

  for (int k0 = 0; k0 < K; k0 += BK) {
    float4 a0 = *(const float4*)(Ap0 + k0);
    float4 a1 = *(const float4*)(Ap1 + k0);
    float4 b0 = *(const float4*)(Wp + (size_t)k0 * N);
    As[ak + 0][am] = a0.x; As[ak + 1][am] = a0.y;
    As[ak + 2][am] = a0.z; As[ak + 3][am] = a0.w;
    As[ak + 0][am + 64] = a1.x; As[ak + 1][am + 64] = a1.y;
    As[ak + 2][am + 64] = a1.z; As[ak + 3][am + 64] = a1.w;
    *(float4*)&Bs[bk][bn4] = b0;
    __syncthreads();
#pragma unroll
    for (int kk = 0; kk < BK; kk++) {
      float4 aA = *(const float4*)&As[kk][ty * 8];
      float4 aB = *(const float4*)&As[kk][ty * 8 + 4];
      float4 bb = *(const float4*)&Bs[kk][tx * 4];
      float av[8] = {aA.x, aA.y, aA.z, aA.w, aB.x, aB.y, aB.z, aB.w};
      float bv[4] = {bb.x, bb.y, bb.z, bb.w};
#pragma unroll
      for (int i = 0; i < 8; i++)
#pragma unroll
        for (int j = 0; j < 4; j++) acc[i][j] = fmaf(av[i], bv[j], acc[i][j]);
    }
    __syncthreads();
  }

  float4 b4 = *(const float4*)&bias[bn + tx * 4];
  float bvv[4] = {b4.x, b4.y, b4.z, b4.w};
#pragma unroll
  for (int i = 0; i < 8; i++) {
    int m = bm + ty * 8 + i;
    float* cp = C + (size_t)m * N + bn + tx * 4;
    float o[4];
#pragma unroll
    for (int j = 0; j < 4; j++) {
      float v = acc[i][j] + bvv[j];
      if (EPI == 1) v = v * v;
      else if (EPI == 2) v = 0.5f * v * (1.0f + erff(v * 0.70710678118654752f));
      o[j] = v;
    }
    float4 ov = make_float4(o[0], o[1], o[2], o[3]);
    if (EPI == 3) {
      float4 old = *(const float4*)cp;
      ov.x += old.x; ov.y += old.y; ov.z += old.z; ov.w += old.w;
    }
    *(float4*)cp = ov;
  }
}

// ---------------------------------------------------------------------------
// Per-chunk summaries: Skv[m][n] = sum_g k[g][m]*v[g][n], ksum[m] = sum_g k[g][m]
// grid = kB*kH*kNC, block = 256
__global__ __launch_bounds__(256) void attn_sums_kernel(
    const float* __restrict__ k, const float* __restrict__ v,
    float* __restrict__ sums) {
  int blk = blockIdx.x;              // b*(H*NC) + h*NC + c
  int c = blk & (kNC - 1);
  int hh = (blk >> 5) & (kH - 1);
  int b = blk >> 8;
  int g0 = c * kCHUNK;
  __shared__ float ks[kCHUNK][kHD];
  __shared__ float vs[kCHUNK][kHD];
  const float* kbase = k + ((size_t)b * kG + g0) * kD + hh * kHD;
  const float* vbase = v + ((size_t)b * kG + g0) * kD + hh * kHD;
#pragma unroll
  for (int r = 0; r < 2; r++) {
    int e = threadIdx.x + r * 256;
    int i = e >> 3, j = (e & 7) * 4;
    *(float4*)&ks[i][j] = *(const float4*)&kbase[(size_t)i * kD + j];
    *(float4*)&vs[i][j] = *(const float4*)&vbase[(size_t)i * kD + j];
  }
  __syncthreads();
  int m = threadIdx.x >> 3, n0 = (threadIdx.x & 7) * 4;
  float a0 = 0, a1 = 0, a2 = 0, a3 = 0;
  for (int i = 0; i < kCHUNK; i++) {
    float km = ks[i][m];
    float4 v4 = *(const float4*)&vs[i][n0];
    a0 = fmaf(km, v4.x, a0); a1 = fmaf(km, v4.y, a1);
    a2 = fmaf(km, v4.z, a2); a3 = fmaf(km, v4.w, a3);
  }
  float* outp = sums + (size_t)blk * kSUMSZ;
  *(float4*)&outp[m * kHD + n0] = make_float4(a0, a1, a2, a3);
  if (threadIdx.x < kHD) {
    float s = 0;
    for (int i = 0; i < kCHUNK; i++) s += ks[i][threadIdx.x];
    outp[kHD * kHD + threadIdx.x] = s;
  }
}

// ---------------------------------------------------------------------------
// Exclusive prefix scan over chunks, in place. grid = kB*kH, block = 256
__global__ void attn_scan_kernel(float* __restrict__ sums) {
  int bh = blockIdx.x;
  float* base = sums + (size_t)bh * kNC * kSUMSZ;
  for (int e = threadIdx.x; e < kSUMSZ; e += 256) {
    float run = 0;
    for (int c = 0; c < kNC; c++) {
      float* p = base + (size_t)c * kSUMSZ + e;
      float tmp = *p;
      *p = run;
      run += tmp;
    }
  }
}

// ---------------------------------------------------------------------------
// Per-chunk output: o = (QK^T masked)·V + Q·S_prev, normalized; h += o
// grid = kB*kH*kNC, block = 256
__global__ __launch_bounds__(256) void attn_out_kernel(
    const float* __restrict__ q, const float* __restrict__ k,
    const float* __restrict__ v, const float* __restrict__ sums,
    float* __restrict__ h) {
  int blk = blockIdx.x;
  int c = blk & (kNC - 1);
  int hh = (blk >> 5) & (kH - 1);
  int b = blk >> 8;
  int g0 = c * kCHUNK;
  __shared__ float qs[kCHUNK][kHD];
  __shared__ float ks[kCHUNK][kHD];
  __shared__ float vs[kCHUNK][kHD];
  __shared__ float Sf[kHD * kHD];
  __shared__ float ksum[kHD];
  __shared__ float Amat[kCHUNK][kCHUNK + 1];   // +1: avoid 8-way bank conflict
  __shared__ float den_s[kCHUNK];
  int t = threadIdx.x;
  const float* qbase = q + ((size_t)b * kG + g0) * kD + hh * kHD;
  const float* kbase = k + ((size_t)b * kG + g0) * kD + hh * kHD;
  const float* vbase = v + ((size_t)b * kG + g0) * kD + hh * kHD;
#pragma unroll
  for (int r = 0; r < 2; r++) {
    int e = t + r * 256;
    int i = e >> 3, j = (e & 7) * 4;
    *(float4*)&qs[i][j] = *(const float4*)&qbase[(size_t)i * kD + j];
    *(float4*)&ks[i][j] = *(const float4*)&kbase[(size_t)i * kD + j];
    *(float4*)&vs[i][j] = *(const float4*)&vbase[(size_t)i * kD + j];
  }
  const float* sp = sums + (size_t)blk * kSUMSZ;
  *(float4*)&Sf[t * 4] = *(const float4*)&sp[t * 4];           // 256*4 = 1024
  if (t < 8) *(float4*)&ksum[t * 4] = *(const float4*)&sp[kHD * kHD + t * 4];
  __syncthreads();

  // Stage 1: Amat[i][j] = q_i . k_j  (full tile; causal mask applied later)
  {
    int i = t >> 2;
    int j0 = (t & 3) * 16;
    float qr[kHD];
#pragma unroll
    for (int m4 = 0; m4 < kHD / 4; m4++) {
      float4 qv = *(const float4*)&qs[i][m4 * 4];
      qr[m4 * 4 + 0] = qv.x; qr[m4 * 4 + 1] = qv.y;
      qr[m4 * 4 + 2] = qv.z; qr[m4 * 4 + 3] = qv.w;
    }
    for (int jj = 0; jj < 16; jj++) {
      int j = j0 + jj;
      float s = 0;
#pragma unroll
      for (int m4 = 0; m4 < kHD / 4; m4++) {
        float4 kv = *(const float4*)&ks[j][m4 * 4];
        s = fmaf(qr[m4 * 4 + 0], kv.x, s);
        s = fmaf(qr[m4 * 4 + 1], kv.y, s);
        s = fmaf(qr[m4 * 4 + 2], kv.z, s);
        s = fmaf(qr[m4 * 4 + 3], kv.w, s);
      }
      Amat[i][j] = s;
    }
  }
  __syncthreads();

  // den_i = sum_{j<=i} A[i][j] + q_i . ksum_prev
  if (t < kCHUNK) {
    float dsum = 0;
    for (int j = 0; j <= t; j++) dsum += Amat[t][j];
#pragma unroll
    for (int m = 0; m < kHD; m++) dsum = fmaf(qs[t][m], ksum[m], dsum);
    den_s[t] = dsum;
  }
  __syncthreads();

  // num_i[n] = sum_{j<=i} A[i][j] v_j[n] + sum_m q_i[m] S[m][n] ; h += num/den
  float* hbase = h + ((size_t)b * kG + g0) * kD + hh * kHD;
#pragma unroll
  for (int uu = 0; uu < 2; uu++) {
    int u = t + uu * 256;
    int i = u >> 3, n0 = (u & 7) * 4;
    float ax = 0, ay = 0, az = 0, aw = 0;
#pragma unroll
    for (int m = 0; m < kHD; m++) {
      float qm = qs[i][m];
      float4 s4 = *(const float4*)&Sf[m * kHD + n0];
      ax = fmaf(qm, s4.x, ax); ay = fmaf(qm, s4.y, ay);
      az = fmaf(qm, s4.z, az); aw = fmaf(qm, s4.w, aw);
    }
    for (int j = 0; j <= i; j++) {
      float w = Amat[i][j];
      float4 vv = *(const float4*)&vs[j][n0];
      ax = fmaf(w, vv.x, ax); ay = fmaf(w, vv.y, ay);
      az = fmaf(w, vv.z, az); aw = fmaf(w, vv.w, aw);
    }
    float dinv = 1.0f / (den_s[i] + 1e-16f);
    float* hp = hbase + (size_t)i * kD + n0;
    float4 old = *(const float4*)hp;
    *(float4*)hp = make_float4(old.x + ax * dinv, old.y + ay * dinv,
                               old.z + az * dinv, old.w + aw * dinv);
  }
}

// ---------------------------------------------------------------------------
// out[row] = h[row,:] . Wo + bo
__global__ void final_kernel(const float* __restrict__ h,
                             const float* __restrict__ Wo,
                             const float* __restrict__ bo,
                             float* __restrict__ out) {
  int row = blockIdx.x;
  int t = threadIdx.x;
  float v = h[(size_t)row * kD + t] * Wo[t];
#pragma unroll
  for (int o = 32; o > 0; o >>= 1) v += __shfl_down(v, o);
  __shared__ float ss[4];
  if ((t & 63) == 0) ss[t >> 6] = v;
  __syncthreads();
  if (t == 0) out[row] = ss[0] + ss[1] + ss[2] + ss[3] + bo[0];
}

// ---------------------------------------------------------------------------
extern "C" void kernel_launch(void* const* d_in, const int* in_sizes, int n_in,
                              void* d_out, int out_size, void* d_ws, size_t ws_size,
                              hipStream_t stream) {
  const float* x    = (const float*)d_in[0];
  const float* ge   = (const float*)d_in[1];
  const float* Wq   = (const float*)d_in[2];
  const float* bq   = (const float*)d_in[3];
  const float* Wk   = (const float*)d_in[4];
  const float* bk   = (const float*)d_in[5];
  const float* Wv   = (const float*)d_in[6];
  const float* bv   = (const float*)d_in[7];
  const float* ln1g = (const float*)d_in[8];
  const float* ln1b = (const float*)d_in[9];
  const float* ln2g = (const float*)d_in[10];
  const float* ln2b = (const float*)d_in[11];
  const float* WU   = (const float*)d_in[12];
  const float* bU   = (const float*)d_in[13];
  const float* WV   = (const float*)d_in[14];
  const float* bV   = (const float*)d_in[15];
  const float* Wo   = (const float*)d_in[16];
  const float* bo   = (const float*)d_in[17];
  float* out = (float*)d_out;

  // Workspace layout (floats). u aliases q/k/v/sums — those are dead during FFN.
  float* ws   = (float*)d_ws;
  float* h    = ws;                  // 2,097,152
  float* z    = ws + 2097152;        // 2,097,152
  float* qb   = ws + 4194304;        // 2,097,152
  float* kb   = ws + 6291456;        // 2,097,152
  float* vb   = ws + 8388608;        // 2,097,152
  float* sums = ws + 10485760;       // 1,081,344
  float* u    = ws + 4194304;        // 8,388,608 (aliases qb/kb/vb/sums)

  dim3 blk256(256);
  embed_kernel<<<kBG * kD / 256, blk256, 0, stream>>>(x, ge, h);
  for (int l = 0; l < kL; l++) {
    ln_kernel<<<kBG, blk256, 0, stream>>>(h, ln1g + l * kD, ln1b + l * kD, z);
    gemm_kernel<1><<<dim3(kD / 64, kBG / 128), blk256, 0, stream>>>(
        z, Wq + (size_t)l * kD * kD, bq + l * kD, qb, kBG, kD, kD);
    gemm_kernel<1><<<dim3(kD / 64, kBG / 128), blk256, 0, stream>>>(
        z, Wk + (size_t)l * kD * kD, bk + l * kD, kb, kBG, kD, kD);
    gemm_kernel<0><<<dim3(kD / 64, kBG / 128), blk256, 0, stream>>>(
        z, Wv + (size_t)l * kD * kD, bv + l * kD, vb, kBG, kD, kD);
    attn_sums_kernel<<<kB * kH * kNC, blk256, 0, stream>>>(kb, vb, sums);
    attn_scan_kernel<<<kB * kH, blk256, 0, stream>>>(sums);
    attn_out_kernel<<<kB * kH * kNC, blk256, 0, stream>>>(qb, kb, vb, sums, h);
    ln_kernel<<<kBG, blk256, 0, stream>>>(h, ln2g + l * kD, ln2b + l * kD, z);
    gemm_kernel<2><<<dim3(kFFN / 64, kBG / 128), blk256, 0, stream>>>(
        z, WU + (size_t)l * kD * kFFN, bU + l * kFFN, u, kBG, kFFN, kD);
    gemm_kernel<3><<<dim3(kD / 64, kBG / 128), blk256, 0, stream>>>(
        u, WV + (size_t)l * kFFN * kD, bV + l * kD, h, kBG, kD, kFFN);
  }
  final_kernel<<<kBG, blk256, 0, stream>>>(h, Wo, bo, out);
}

// Round 2
// 604.114 us; speedup vs baseline: 2.3076x; 2.3076x over previous
//
#include <hip/hip_runtime.h>
#include <math.h>

// Problem constants
constexpr int kB = 4, kG = 2048, kD = 256, kH = 8, kHD = 32, kL = 4, kFFN = 1024;
constexpr int kBG = kB * kG;                  // 8192 tokens
constexpr int kCHUNK = 64;                    // linear-attn chunk length
constexpr int kNC = kG / kCHUNK;              // 32 chunks per sequence
constexpr int kSUMSZ = kHD * kHD + kHD;       // 1056 floats per chunk-state
constexpr int kQKVN = 3 * kD;                 // 768 fused QKV columns

typedef __bf16 bf16x8 __attribute__((ext_vector_type(8)));
typedef unsigned short ushort8 __attribute__((ext_vector_type(8)));
typedef float floatx4 __attribute__((ext_vector_type(4)));

__device__ __forceinline__ unsigned short f2bf(float f) {
  unsigned int u = __float_as_uint(f);
  u += 0x7fff + ((u >> 16) & 1);              // round-to-nearest-even
  return (unsigned short)(u >> 16);
}

__device__ __forceinline__ void load_lds_16(const void* g, void* l) {
  __builtin_amdgcn_global_load_lds((const __attribute__((address_space(1))) void*)g,
                                   (__attribute__((address_space(3))) void*)l,
                                   16, 0, 0);
}

// ---------------------------------------------------------------------------
// h[b,g,d] = gene_emb[g,d] + ree(x[b,g], d)
__global__ void embed_kernel(const float* __restrict__ x,
                             const float* __restrict__ ge,
                             float* __restrict__ h) {
  int idx = blockIdx.x * 256 + threadIdx.x;   // over kB*kG*kD = 2^21
  int d = idx & (kD - 1);
  int g = (idx >> 8) & (kG - 1);
  int b = idx >> 19;
  float xv = x[b * kG + g];
  int i = d & 127;
  float inv = expf(-(float)i * (4.6051701859880914f / 128.0f));  // 100^(-i/128)
  float f = xv * inv;
  float r = (d < 128) ? sinf(f) : cosf(f);
  if (xv == -10.0f) r = 0.0f;
  h[idx] = ge[g * kD + d] + r;
}

// ---------------------------------------------------------------------------
// Weight conversion: fp32 K-major -> bf16 N-major (transposed), plus QKV bias
// packing. One launch covers all layers.
// Per layer: 192 tiles Wq/Wk/Wv (32x32 each), 256 tiles WU, 256 tiles WV.
__global__ void convert_weights_kernel(
    const float* __restrict__ Wq, const float* __restrict__ Wk,
    const float* __restrict__ Wv, const float* __restrict__ WU,
    const float* __restrict__ WV, const float* __restrict__ bq,
    const float* __restrict__ bk, const float* __restrict__ bv,
    unsigned short* __restrict__ Wqkv_t, unsigned short* __restrict__ WU_t,
    unsigned short* __restrict__ WV_t, float* __restrict__ bias_qkv) {
  int blk = blockIdx.x;
  if (blk >= kL * 704) {                       // bias-packing tail blocks
    int idx = (blk - kL * 704) * 256 + threadIdx.x;
    if (idx < kL * kQKVN) {
      int l = idx / kQKVN, n = idx % kQKVN;
      float v = (n < 256) ? bq[l * 256 + n]
              : (n < 512) ? bk[l * 256 + n - 256]
                          : bv[l * 256 + n - 512];
      bias_qkv[idx] = v;
    }
    return;
  }
  int l = blk / 704, id = blk % 704;
  const float* src;
  unsigned short* dst;
  int Ksrc, Nsrc, kt, nt;
  if (id < 192) {
    int m = id >> 6, tid = id & 63;
    src = (m == 0 ? Wq : m == 1 ? Wk : Wv) + (size_t)l * 256 * 256;
    dst = Wqkv_t + (size_t)l * kQKVN * 256 + (size_t)m * 256 * 256;
    Ksrc = 256; Nsrc = 256; kt = tid >> 3; nt = tid & 7;
  } else if (id < 448) {
    int tid = id - 192;
    src = WU + (size_t)l * 256 * 1024;
    dst = WU_t + (size_t)l * 1024 * 256;
    Ksrc = 256; Nsrc = 1024; kt = tid >> 5; nt = tid & 31;
  } else {
    int tid = id - 448;
    src = WV + (size_t)l * 1024 * 256;
    dst = WV_t + (size_t)l * 256 * 1024;
    Ksrc = 1024; Nsrc = 256; kt = tid >> 3; nt = tid & 7;
  }
  __shared__ float s[32][33];
  int tx = threadIdx.x & 31, ty = threadIdx.x >> 5;   // 32 x 8
#pragma unroll
  for (int r = 0; r < 4; r++)
    s[ty + r * 8][tx] = src[(size_t)(kt * 32 + ty + r * 8) * Nsrc + nt * 32 + tx];
  __syncthreads();
#pragma unroll
  for (int r = 0; r < 4; r++)
    dst[(size_t)(nt * 32 + ty + r * 8) * Ksrc + kt * 32 + tx] =
        f2bf(s[tx][ty + r * 8]);
}

// ---------------------------------------------------------------------------
// Row LayerNorm over D=256 -> bf16 output
__global__ void ln_kernel(const float* __restrict__ h,
                          const float* __restrict__ gamma,
                          const float* __restrict__ beta,
                          unsigned short* __restrict__ z) {
  int row = blockIdx.x;
  int t = threadIdx.x;
  float v = h[(size_t)row * kD + t];
  float s = v, sq = v * v;
#pragma unroll
  for (int o = 32; o > 0; o >>= 1) {
    s += __shfl_down(s, o);
    sq += __shfl_down(sq, o);
  }
  __shared__ float s1[4], s2[4];
  if ((t & 63) == 0) { s1[t >> 6] = s; s2[t >> 6] = sq; }
  __syncthreads();
  float mu = (s1[0] + s1[1] + s1[2] + s1[3]) * (1.0f / kD);
  float var = (s2[0] + s2[1] + s2[2] + s2[3]) * (1.0f / kD) - mu * mu;
  float r = rsqrtf(var + 1e-5f);
  z[(size_t)row * kD + t] = f2bf((v - mu) * r * gamma[t] + beta[t]);
}

// ---------------------------------------------------------------------------
// bf16 MFMA GEMM, m97 structure: 128x128 tile, BK=32, global_load_lds staging.
// A: M x K bf16 (row-major), Bt: N x K bf16 (row-major = W transposed).
// EPI: 1 = fused QKV (square cols < 512), fp32 out
//      2 = exact gelu, bf16 out
//      3 = residual add (Cres == C), fp32 out
template <int EPI>
__global__ __launch_bounds__(256) void mfma_gemm(
    const unsigned short* __restrict__ A, const unsigned short* __restrict__ Bt,
    const float* __restrict__ bias, void* __restrict__ Cout,
    const float* __restrict__ Cres, int M, int N, int K) {
  __shared__ unsigned short As[128 * 32];   // row-major [row][k], 8 KB
  __shared__ unsigned short Bs[128 * 32];
  const int t = threadIdx.x;
  const int w = t >> 6, lane = t & 63;
  const int bm = blockIdx.y * 128, bn = blockIdx.x * 128;
  const int wm = (w >> 1) * 64, wn = (w & 1) * 64;

  // Staging source pointers: chunk c = w*2+r covers rows c*16..c*16+15 of tile.
  const int srow = (lane >> 2);          // 0..15 within chunk
  const int skof = (lane & 3) * 8;       // k element offset of 16B piece
  const unsigned short* ap0 = A + (size_t)(bm + w * 32 + srow) * K + skof;
  const unsigned short* ap1 = ap0 + (size_t)16 * K;
  const unsigned short* bp0 = Bt + (size_t)(bn + w * 32 + srow) * K + skof;
  const unsigned short* bp1 = bp0 + (size_t)16 * K;
  unsigned short* asd0 = &As[w * 1024];
  unsigned short* asd1 = &As[w * 1024 + 512];
  unsigned short* bsd0 = &Bs[w * 1024];
  unsigned short* bsd1 = &Bs[w * 1024 + 512];

  floatx4 acc[4][4];
#pragma unroll
  for (int i = 0; i < 4; i++)
#pragma unroll
    for (int j = 0; j < 4; j++) acc[i][j] = (floatx4){0.f, 0.f, 0.f, 0.f};

  const int lm = lane & 15, lq = lane >> 4;
  const unsigned short* afp = &As[(wm + lm) * 32 + lq * 8];
  const unsigned short* bfp = &Bs[(wn + lm) * 32 + lq * 8];

  for (int k0 = 0; k0 < K; k0 += 32) {
    load_lds_16(ap0 + k0, asd0);
    load_lds_16(ap1 + k0, asd1);
    load_lds_16(bp0 + k0, bsd0);
    load_lds_16(bp1 + k0, bsd1);
    __syncthreads();                       // drains vmcnt(0): staging complete
    bf16x8 af[4], bfr[4];
#pragma unroll
    for (int i = 0; i < 4; i++)
      af[i] = __builtin_bit_cast(bf16x8,
          *reinterpret_cast<const ushort8*>(afp + i * 16 * 32));
#pragma unroll
    for (int j = 0; j < 4; j++)
      bfr[j] = __builtin_bit_cast(bf16x8,
          *reinterpret_cast<const ushort8*>(bfp + j * 16 * 32));
#pragma unroll
    for (int i = 0; i < 4; i++)
#pragma unroll
      for (int j = 0; j < 4; j++)
        acc[i][j] = __builtin_amdgcn_mfma_f32_16x16x32_bf16(af[i], bfr[j],
                                                            acc[i][j], 0, 0, 0);
    __syncthreads();                       // LDS safe to overwrite
  }

  // Epilogue. C/D layout: col = lane&15, row = (lane>>4)*4 + reg.
  const int r0 = bm + wm + lq * 4;
  const int c0 = bn + wn + lm;
#pragma unroll
  for (int j = 0; j < 4; j++) {
    int col = c0 + j * 16;
    float bv = bias[col];
#pragma unroll
    for (int i = 0; i < 4; i++) {
      int rowb = r0 + i * 16;
#pragma unroll
      for (int r = 0; r < 4; r++) {
        int row = rowb + r;
        float v = acc[i][j][r] + bv;
        size_t idx = (size_t)row * N + col;
        if (EPI == 1) {
          ((float*)Cout)[idx] = (col < 512) ? v * v : v;
        } else if (EPI == 2) {
          float g = 0.5f * v * (1.0f + erff(v * 0.70710678118654752f));
          ((unsigned short*)Cout)[idx] = f2bf(g);
        } else {
          ((float*)Cout)[idx] = Cres[idx] + v;
        }
      }
    }
  }
}

// ---------------------------------------------------------------------------
// Per-chunk summaries from fused qkv buffer (row stride 768).
// Skv[m][n] = sum_g k[g][m]*v[g][n], ksum[m] = sum_g k[g][m]
__global__ __launch_bounds__(256) void attn_sums_kernel(
    const float* __restrict__ qkv, float* __restrict__ sums) {
  int blk = blockIdx.x;              // b*(H*NC) + h*NC + c
  int c = blk & (kNC - 1);
  int hh = (blk >> 5) & (kH - 1);
  int b = blk >> 8;
  int g0 = c * kCHUNK;
  __shared__ float ks[kCHUNK][kHD];
  __shared__ float vs[kCHUNK][kHD];
  const float* kbase = qkv + (size_t)(b * kG + g0) * kQKVN + 256 + hh * kHD;
  const float* vbase = qkv + (size_t)(b * kG + g0) * kQKVN + 512 + hh * kHD;
#pragma unroll
  for (int r = 0; r < 2; r++) {
    int e = threadIdx.x + r * 256;
    int i = e >> 3, j = (e & 7) * 4;
    *(float4*)&ks[i][j] = *(const float4*)&kbase[(size_t)i * kQKVN + j];
    *(float4*)&vs[i][j] = *(const float4*)&vbase[(size_t)i * kQKVN + j];
  }
  __syncthreads();
  int m = threadIdx.x >> 3, n0 = (threadIdx.x & 7) * 4;
  float a0 = 0, a1 = 0, a2 = 0, a3 = 0;
  for (int i = 0; i < kCHUNK; i++) {
    float km = ks[i][m];
    float4 v4 = *(const float4*)&vs[i][n0];
    a0 = fmaf(km, v4.x, a0); a1 = fmaf(km, v4.y, a1);
    a2 = fmaf(km, v4.z, a2); a3 = fmaf(km, v4.w, a3);
  }
  float* outp = sums + (size_t)blk * kSUMSZ;
  *(float4*)&outp[m * kHD + n0] = make_float4(a0, a1, a2, a3);
  if (threadIdx.x < kHD) {
    float s = 0;
    for (int i = 0; i < kCHUNK; i++) s += ks[i][threadIdx.x];
    outp[kHD * kHD + threadIdx.x] = s;
  }
}

// ---------------------------------------------------------------------------
// Exclusive prefix scan over chunks, in place. grid = kB*kH
__global__ void attn_scan_kernel(float* __restrict__ sums) {
  int bh = blockIdx.x;
  float* base = sums + (size_t)bh * kNC * kSUMSZ;
  for (int e = threadIdx.x; e < kSUMSZ; e += 256) {
    float run = 0;
    for (int c = 0; c < kNC; c++) {
      float* p = base + (size_t)c * kSUMSZ + e;
      float tmp = *p;
      *p = run;
      run += tmp;
    }
  }
}

// ---------------------------------------------------------------------------
// Per-chunk output: o = (QK^T masked)·V + Q·S_prev, normalized; h += o
__global__ __launch_bounds__(256) void attn_out_kernel(
    const float* __restrict__ qkv, const float* __restrict__ sums,
    float* __restrict__ h) {
  int blk = blockIdx.x;
  int c = blk & (kNC - 1);
  int hh = (blk >> 5) & (kH - 1);
  int b = blk >> 8;
  int g0 = c * kCHUNK;
  __shared__ float qs[kCHUNK][kHD];
  __shared__ float ks[kCHUNK][kHD];
  __shared__ float vs[kCHUNK][kHD];
  __shared__ float Sf[kHD * kHD];
  __shared__ float ksum[kHD];
  __shared__ float Amat[kCHUNK][kCHUNK + 1];
  __shared__ float den_s[kCHUNK];
  int t = threadIdx.x;
  const float* base = qkv + (size_t)(b * kG + g0) * kQKVN + hh * kHD;
#pragma unroll
  for (int r = 0; r < 2; r++) {
    int e = t + r * 256;
    int i = e >> 3, j = (e & 7) * 4;
    *(float4*)&qs[i][j] = *(const float4*)&base[(size_t)i * kQKVN + j];
    *(float4*)&ks[i][j] = *(const float4*)&base[(size_t)i * kQKVN + 256 + j];
    *(float4*)&vs[i][j] = *(const float4*)&base[(size_t)i * kQKVN + 512 + j];
  }
  const float* sp = sums + (size_t)blk * kSUMSZ;
  *(float4*)&Sf[t * 4] = *(const float4*)&sp[t * 4];
  if (t < 8) *(float4*)&ksum[t * 4] = *(const float4*)&sp[kHD * kHD + t * 4];
  __syncthreads();

  // Amat[i][j] = q_i . k_j
  {
    int i = t >> 2;
    int j0 = (t & 3) * 16;
    float qr[kHD];
#pragma unroll
    for (int m4 = 0; m4 < kHD / 4; m4++) {
      float4 qv = *(const float4*)&qs[i][m4 * 4];
      qr[m4 * 4 + 0] = qv.x; qr[m4 * 4 + 1] = qv.y;
      qr[m4 * 4 + 2] = qv.z; qr[m4 * 4 + 3] = qv.w;
    }
    for (int jj = 0; jj < 16; jj++) {
      int j = j0 + jj;
      float s = 0;
#pragma unroll
      for (int m4 = 0; m4 < kHD / 4; m4++) {
        float4 kv = *(const float4*)&ks[j][m4 * 4];
        s = fmaf(qr[m4 * 4 + 0], kv.x, s);
        s = fmaf(qr[m4 * 4 + 1], kv.y, s);
        s = fmaf(qr[m4 * 4 + 2], kv.z, s);
        s = fmaf(qr[m4 * 4 + 3], kv.w, s);
      }
      Amat[i][j] = s;
    }
  }
  __syncthreads();

  if (t < kCHUNK) {
    float dsum = 0;
    for (int j = 0; j <= t; j++) dsum += Amat[t][j];
#pragma unroll
    for (int m = 0; m < kHD; m++) dsum = fmaf(qs[t][m], ksum[m], dsum);
    den_s[t] = dsum;
  }
  __syncthreads();

  float* hbase = h + (size_t)(b * kG + g0) * kD + hh * kHD;
#pragma unroll
  for (int uu = 0; uu < 2; uu++) {
    int u = t + uu * 256;
    int i = u >> 3, n0 = (u & 7) * 4;
    float ax = 0, ay = 0, az = 0, aw = 0;
#pragma unroll
    for (int m = 0; m < kHD; m++) {
      float qm = qs[i][m];
      float4 s4 = *(const float4*)&Sf[m * kHD + n0];
      ax = fmaf(qm, s4.x, ax); ay = fmaf(qm, s4.y, ay);
      az = fmaf(qm, s4.z, az); aw = fmaf(qm, s4.w, aw);
    }
    for (int j = 0; j <= i; j++) {
      float w = Amat[i][j];
      float4 vv = *(const float4*)&vs[j][n0];
      ax = fmaf(w, vv.x, ax); ay = fmaf(w, vv.y, ay);
      az = fmaf(w, vv.z, az); aw = fmaf(w, vv.w, aw);
    }
    float dinv = 1.0f / (den_s[i] + 1e-16f);
    float* hp = hbase + (size_t)i * kD + n0;
    float4 old = *(const float4*)hp;
    *(float4*)hp = make_float4(old.x + ax * dinv, old.y + ay * dinv,
                               old.z + az * dinv, old.w + aw * dinv);
  }
}

// ---------------------------------------------------------------------------
__global__ void final_kernel(const float* __restrict__ h,
                             const float* __restrict__ Wo,
                             const float* __restrict__ bo,
                             float* __restrict__ out) {
  int row = blockIdx.x;
  int t = threadIdx.x;
  float v = h[(size_t)row * kD + t] * Wo[t];
#pragma unroll
  for (int o = 32; o > 0; o >>= 1) v += __shfl_down(v, o);
  __shared__ float ss[4];
  if ((t & 63) == 0) ss[t >> 6] = v;
  __syncthreads();
  if (t == 0) out[row] = ss[0] + ss[1] + ss[2] + ss[3] + bo[0];
}

// ---------------------------------------------------------------------------
extern "C" void kernel_launch(void* const* d_in, const int* in_sizes, int n_in,
                              void* d_out, int out_size, void* d_ws, size_t ws_size,
                              hipStream_t stream) {
  const float* x    = (const float*)d_in[0];
  const float* ge   = (const float*)d_in[1];
  const float* Wq   = (const float*)d_in[2];
  const float* bq   = (const float*)d_in[3];
  const float* Wk   = (const float*)d_in[4];
  const float* bk   = (const float*)d_in[5];
  const float* Wv   = (const float*)d_in[6];
  const float* bv   = (const float*)d_in[7];
  const float* ln1g = (const float*)d_in[8];
  const float* ln1b = (const float*)d_in[9];
  const float* ln2g = (const float*)d_in[10];
  const float* ln2b = (const float*)d_in[11];
  const float* WU   = (const float*)d_in[12];
  const float* bU   = (const float*)d_in[13];
  const float* WV   = (const float*)d_in[14];
  const float* bV   = (const float*)d_in[15];
  const float* Wo   = (const float*)d_in[16];
  const float* bo   = (const float*)d_in[17];
  float* out = (float*)d_out;

  // Workspace layout (fp32 slot offsets; all 16B-aligned):
  float* ws = (float*)d_ws;
  float*          h       = ws;                        // 2,097,152 f32
  unsigned short* zb      = (unsigned short*)(ws + 2097152);   // 2,097,152 bf16
  float*          qkv     = ws + 3145728;              // 6,291,456 f32 [8192][768]
  unsigned short* u       = (unsigned short*)qkv;      // aliases qkv (disjoint phases)
  float*          sums    = ws + 9437184;              // 1,081,344 f32
  unsigned short* Wqkv_t  = (unsigned short*)(ws + 10518528);  // 786,432 bf16
  unsigned short* WU_t    = (unsigned short*)(ws + 10911744);  // 1,048,576 bf16
  unsigned short* WV_t    = (unsigned short*)(ws + 11436032);  // 1,048,576 bf16
  float*          bias_qkv= ws + 11960320;             // 3,072 f32

  dim3 blk256(256);
  convert_weights_kernel<<<kL * 704 + 12, blk256, 0, stream>>>(
      Wq, Wk, Wv, WU, WV, bq, bk, bv, Wqkv_t, WU_t, WV_t, bias_qkv);
  embed_kernel<<<kBG * kD / 256, blk256, 0, stream>>>(x, ge, h);
  for (int l = 0; l < kL; l++) {
    ln_kernel<<<kBG, blk256, 0, stream>>>(h, ln1g + l * kD, ln1b + l * kD, zb);
    mfma_gemm<1><<<dim3(kQKVN / 128, kBG / 128), blk256, 0, stream>>>(
        zb, Wqkv_t + (size_t)l * kQKVN * kD, bias_qkv + l * kQKVN, qkv, nullptr,
        kBG, kQKVN, kD);
    attn_sums_kernel<<<kB * kH * kNC, blk256, 0, stream>>>(qkv, sums);
    attn_scan_kernel<<<kB * kH, blk256, 0, stream>>>(sums);
    attn_out_kernel<<<kB * kH * kNC, blk256, 0, stream>>>(qkv, sums, h);
    ln_kernel<<<kBG, blk256, 0, stream>>>(h, ln2g + l * kD, ln2b + l * kD, zb);
    mfma_gemm<2><<<dim3(kFFN / 128, kBG / 128), blk256, 0, stream>>>(
        zb, WU_t + (size_t)l * kFFN * kD, bU + l * kFFN, u, nullptr,
        kBG, kFFN, kD);
    mfma_gemm<3><<<dim3(kD / 128, kBG / 128), blk256, 0, stream>>>(
        u, WV_t + (size_t)l * kD * kFFN, bV + l * kD, h, h,
        kBG, kD, kFFN);
  }
  final_kernel<<<kBG, blk256, 0, stream>>>(h, Wo, bo, out);
}

// Round 3
// 449.155 us; speedup vs baseline: 3.1038x; 1.3450x over previous
//
#include <hip/hip_runtime.h>
#include <math.h>

// Problem constants
constexpr int kB = 4, kG = 2048, kD = 256, kH = 8, kHD = 32, kL = 4, kFFN = 1024;
constexpr int kBG = kB * kG;                  // 8192 tokens
constexpr int kCHUNK = 64;                    // linear-attn chunk length
constexpr int kNC = kG / kCHUNK;              // 32 chunks per sequence
constexpr int kSUMSZ = kHD * kHD + kHD;       // 1056 floats per chunk-state
constexpr int kQKVN = 3 * kD;                 // 768 fused QKV columns

typedef __bf16 bf16x8 __attribute__((ext_vector_type(8)));
typedef unsigned short ushort8 __attribute__((ext_vector_type(8)));
typedef float floatx4 __attribute__((ext_vector_type(4)));

__device__ __forceinline__ unsigned short f2bf(float f) {
  unsigned int u = __float_as_uint(f);
  u += 0x7fff + ((u >> 16) & 1);              // round-to-nearest-even
  return (unsigned short)(u >> 16);
}

__device__ __forceinline__ void load_lds_16(const void* g, void* l) {
  __builtin_amdgcn_global_load_lds((const __attribute__((address_space(1))) void*)g,
                                   (__attribute__((address_space(3))) void*)l,
                                   16, 0, 0);
}

// ---------------------------------------------------------------------------
// h[b,g,d] = gene_emb[g,d] + ree(x[b,g], d)
__global__ void embed_kernel(const float* __restrict__ x,
                             const float* __restrict__ ge,
                             float* __restrict__ h) {
  int idx = blockIdx.x * 256 + threadIdx.x;   // over kB*kG*kD = 2^21
  int d = idx & (kD - 1);
  int g = (idx >> 8) & (kG - 1);
  int b = idx >> 19;
  float xv = x[b * kG + g];
  int i = d & 127;
  float inv = expf(-(float)i * (4.6051701859880914f / 128.0f));  // 100^(-i/128)
  float f = xv * inv;
  float r = (d < 128) ? sinf(f) : cosf(f);
  if (xv == -10.0f) r = 0.0f;
  h[idx] = ge[g * kD + d] + r;
}

// ---------------------------------------------------------------------------
// Weight conversion: fp32 K-major -> bf16 N-major (transposed), plus QKV bias
// packing. One launch covers all layers.
__global__ void convert_weights_kernel(
    const float* __restrict__ Wq, const float* __restrict__ Wk,
    const float* __restrict__ Wv, const float* __restrict__ WU,
    const float* __restrict__ WV, const float* __restrict__ bq,
    const float* __restrict__ bk, const float* __restrict__ bv,
    unsigned short* __restrict__ Wqkv_t, unsigned short* __restrict__ WU_t,
    unsigned short* __restrict__ WV_t, float* __restrict__ bias_qkv) {
  int blk = blockIdx.x;
  if (blk >= kL * 704) {                       // bias-packing tail blocks
    int idx = (blk - kL * 704) * 256 + threadIdx.x;
    if (idx < kL * kQKVN) {
      int l = idx / kQKVN, n = idx % kQKVN;
      float v = (n < 256) ? bq[l * 256 + n]
              : (n < 512) ? bk[l * 256 + n - 256]
                          : bv[l * 256 + n - 512];
      bias_qkv[idx] = v;
    }
    return;
  }
  int l = blk / 704, id = blk % 704;
  const float* src;
  unsigned short* dst;
  int Ksrc, Nsrc, kt, nt;
  if (id < 192) {
    int m = id >> 6, tid = id & 63;
    src = (m == 0 ? Wq : m == 1 ? Wk : Wv) + (size_t)l * 256 * 256;
    dst = Wqkv_t + (size_t)l * kQKVN * 256 + (size_t)m * 256 * 256;
    Ksrc = 256; Nsrc = 256; kt = tid >> 3; nt = tid & 7;
  } else if (id < 448) {
    int tid = id - 192;
    src = WU + (size_t)l * 256 * 1024;
    dst = WU_t + (size_t)l * 1024 * 256;
    Ksrc = 256; Nsrc = 1024; kt = tid >> 5; nt = tid & 31;
  } else {
    int tid = id - 448;
    src = WV + (size_t)l * 1024 * 256;
    dst = WV_t + (size_t)l * 256 * 1024;
    Ksrc = 1024; Nsrc = 256; kt = tid >> 3; nt = tid & 7;
  }
  __shared__ float s[32][33];
  int tx = threadIdx.x & 31, ty = threadIdx.x >> 5;   // 32 x 8
#pragma unroll
  for (int r = 0; r < 4; r++)
    s[ty + r * 8][tx] = src[(size_t)(kt * 32 + ty + r * 8) * Nsrc + nt * 32 + tx];
  __syncthreads();
#pragma unroll
  for (int r = 0; r < 4; r++)
    dst[(size_t)(nt * 32 + ty + r * 8) * Ksrc + kt * 32 + tx] =
        f2bf(s[tx][ty + r * 8]);
}

// ---------------------------------------------------------------------------
// Row LayerNorm over D=256 -> bf16 output. Wave-per-row, 4 rows/block.
__global__ __launch_bounds__(256) void ln_kernel(
    const float* __restrict__ h, const float* __restrict__ gamma,
    const float* __restrict__ beta, unsigned short* __restrict__ z) {
  int w = threadIdx.x >> 6, lane = threadIdx.x & 63;
  size_t row = (size_t)blockIdx.x * 4 + w;
  float4 v = *(const float4*)&h[row * kD + lane * 4];
  float s = v.x + v.y + v.z + v.w;
  float sq = v.x * v.x + v.y * v.y + v.z * v.z + v.w * v.w;
#pragma unroll
  for (int o = 32; o > 0; o >>= 1) {
    s += __shfl_xor(s, o);
    sq += __shfl_xor(sq, o);
  }
  float mu = s * (1.0f / kD);
  float var = sq * (1.0f / kD) - mu * mu;
  float r = rsqrtf(var + 1e-5f);
  float4 g4 = *(const float4*)&gamma[lane * 4];
  float4 b4 = *(const float4*)&beta[lane * 4];
  float y0 = (v.x - mu) * r * g4.x + b4.x;
  float y1 = (v.y - mu) * r * g4.y + b4.y;
  float y2 = (v.z - mu) * r * g4.z + b4.z;
  float y3 = (v.w - mu) * r * g4.w + b4.w;
  unsigned int u0 = (unsigned int)f2bf(y0) | ((unsigned int)f2bf(y1) << 16);
  unsigned int u1 = (unsigned int)f2bf(y2) | ((unsigned int)f2bf(y3) << 16);
  uint2 uu; uu.x = u0; uu.y = u1;
  *(uint2*)&z[row * kD + lane * 4] = uu;
}

// ---------------------------------------------------------------------------
// bf16 MFMA GEMM, m97 structure: 128xBN tile, BK=32, global_load_lds staging.
// A: M x K bf16 (row-major), Bt: N x K bf16 (row-major = W transposed).
// EPI: 1 = fused QKV (square cols < 512), fp32 out
//      2 = exact gelu, bf16 out
//      3 = residual add (Cres == C), fp32 out
template <int EPI, int BN>
__global__ __launch_bounds__(256) void mfma_gemm(
    const unsigned short* __restrict__ A, const unsigned short* __restrict__ Bt,
    const float* __restrict__ bias, void* __restrict__ Cout,
    const float* __restrict__ Cres, int M, int N, int K) {
  constexpr int NI = (BN == 128) ? 4 : 2;     // 16-row tiles per wave (M)
  constexpr int NJ = 4;                       // 16-col tiles per wave (N)
  __shared__ unsigned short As[128 * 32];
  __shared__ unsigned short Bs[BN * 32];
  const int t = threadIdx.x;
  const int w = t >> 6, lane = t & 63;
  const int bm = blockIdx.y * 128, bn = blockIdx.x * BN;
  const int wm = (BN == 128) ? (w >> 1) * 64 : w * 32;
  const int wn = (BN == 128) ? (w & 1) * 64 : 0;

  const int srow = (lane >> 2);          // 0..15 within 16-row chunk
  const int skof = (lane & 3) * 8;       // k element offset of 16B piece
  const unsigned short* ap0 = A + (size_t)(bm + w * 32 + srow) * K + skof;
  const unsigned short* ap1 = ap0 + (size_t)16 * K;
  unsigned short* asd0 = &As[w * 1024];
  unsigned short* asd1 = &As[w * 1024 + 512];
  const unsigned short* bp0;
  const unsigned short* bp1 = nullptr;
  unsigned short* bsd0;
  unsigned short* bsd1 = nullptr;
  if (BN == 128) {
    bp0 = Bt + (size_t)(bn + w * 32 + srow) * K + skof;
    bp1 = bp0 + (size_t)16 * K;
    bsd0 = &Bs[w * 1024];
    bsd1 = &Bs[w * 1024 + 512];
  } else {
    bp0 = Bt + (size_t)(bn + w * 16 + srow) * K + skof;
    bsd0 = &Bs[w * 512];
  }

  floatx4 acc[NI][NJ];
#pragma unroll
  for (int i = 0; i < NI; i++)
#pragma unroll
    for (int j = 0; j < NJ; j++) acc[i][j] = (floatx4){0.f, 0.f, 0.f, 0.f};

  const int lm = lane & 15, lq = lane >> 4;
  const unsigned short* afp = &As[(wm + lm) * 32 + lq * 8];
  const unsigned short* bfp = &Bs[(wn + lm) * 32 + lq * 8];

  for (int k0 = 0; k0 < K; k0 += 32) {
    load_lds_16(ap0 + k0, asd0);
    load_lds_16(ap1 + k0, asd1);
    load_lds_16(bp0 + k0, bsd0);
    if (BN == 128) load_lds_16(bp1 + k0, bsd1);
    __syncthreads();
    bf16x8 af[NI], bfr[NJ];
#pragma unroll
    for (int i = 0; i < NI; i++)
      af[i] = __builtin_bit_cast(bf16x8,
          *reinterpret_cast<const ushort8*>(afp + i * 16 * 32));
#pragma unroll
    for (int j = 0; j < NJ; j++)
      bfr[j] = __builtin_bit_cast(bf16x8,
          *reinterpret_cast<const ushort8*>(bfp + j * 16 * 32));
#pragma unroll
    for (int i = 0; i < NI; i++)
#pragma unroll
      for (int j = 0; j < NJ; j++)
        acc[i][j] = __builtin_amdgcn_mfma_f32_16x16x32_bf16(af[i], bfr[j],
                                                            acc[i][j], 0, 0, 0);
    __syncthreads();
  }

  // Epilogue. C/D layout: col = lane&15, row = (lane>>4)*4 + reg.
  const int r0 = bm + wm + lq * 4;
  const int c0 = bn + wn + lm;
#pragma unroll
  for (int j = 0; j < NJ; j++) {
    int col = c0 + j * 16;
    float bv = bias[col];
#pragma unroll
    for (int i = 0; i < NI; i++) {
      int rowb = r0 + i * 16;
#pragma unroll
      for (int r = 0; r < 4; r++) {
        int row = rowb + r;
        float v = acc[i][j][r] + bv;
        size_t idx = (size_t)row * N + col;
        if (EPI == 1) {
          ((float*)Cout)[idx] = (col < 512) ? v * v : v;
        } else if (EPI == 2) {
          float g = 0.5f * v * (1.0f + erff(v * 0.70710678118654752f));
          ((unsigned short*)Cout)[idx] = f2bf(g);
        } else {
          ((float*)Cout)[idx] = Cres[idx] + v;
        }
      }
    }
  }
}

// ---------------------------------------------------------------------------
// Per-chunk summaries from fused qkv buffer (row stride 768).
__global__ __launch_bounds__(256) void attn_sums_kernel(
    const float* __restrict__ qkv, float* __restrict__ sums) {
  int blk = blockIdx.x;              // b*(H*NC) + h*NC + c
  int c = blk & (kNC - 1);
  int hh = (blk >> 5) & (kH - 1);
  int b = blk >> 8;
  int g0 = c * kCHUNK;
  __shared__ float ks[kCHUNK][kHD];
  __shared__ float vs[kCHUNK][kHD];
  const float* kbase = qkv + (size_t)(b * kG + g0) * kQKVN + 256 + hh * kHD;
  const float* vbase = qkv + (size_t)(b * kG + g0) * kQKVN + 512 + hh * kHD;
#pragma unroll
  for (int r = 0; r < 2; r++) {
    int e = threadIdx.x + r * 256;
    int i = e >> 3, j = (e & 7) * 4;
    *(float4*)&ks[i][j] = *(const float4*)&kbase[(size_t)i * kQKVN + j];
    *(float4*)&vs[i][j] = *(const float4*)&vbase[(size_t)i * kQKVN + j];
  }
  __syncthreads();
  int m = threadIdx.x >> 3, n0 = (threadIdx.x & 7) * 4;
  float a0 = 0, a1 = 0, a2 = 0, a3 = 0;
  for (int i = 0; i < kCHUNK; i++) {
    float km = ks[i][m];
    float4 v4 = *(const float4*)&vs[i][n0];
    a0 = fmaf(km, v4.x, a0); a1 = fmaf(km, v4.y, a1);
    a2 = fmaf(km, v4.z, a2); a3 = fmaf(km, v4.w, a3);
  }
  float* outp = sums + (size_t)blk * kSUMSZ;
  *(float4*)&outp[m * kHD + n0] = make_float4(a0, a1, a2, a3);
  if (threadIdx.x < kHD) {
    float s = 0;
    for (int i = 0; i < kCHUNK; i++) s += ks[i][threadIdx.x];
    outp[kHD * kHD + threadIdx.x] = s;
  }
}

// ---------------------------------------------------------------------------
// Exclusive prefix scan over chunks. Batched loads (independent, pipelined),
// register prefix, batched stores. grid = kB*kH*5, block = 256.
__global__ void attn_scan_kernel(float* __restrict__ sums) {
  int bh = blockIdx.x / 5, part = blockIdx.x % 5;
  int e = part * 256 + threadIdx.x;
  if (e >= kSUMSZ) return;
  float* base = sums + (size_t)bh * kNC * kSUMSZ + e;
  float v[kNC];
#pragma unroll
  for (int c = 0; c < kNC; c++) v[c] = base[(size_t)c * kSUMSZ];
  float run = 0;
#pragma unroll
  for (int c = 0; c < kNC; c++) {
    float tv = v[c];
    base[(size_t)c * kSUMSZ] = run;
    run += tv;
  }
}

// ---------------------------------------------------------------------------
// Per-chunk output: o = (QK^T masked)·V + Q·S_prev, normalized; h += o
// Conflict-free LDS layout: q/k/v stride 36, Amat stride 68; den folded into
// the A-build stage (reuses q registers, shfl reduce over the 4 j-lanes).
__global__ __launch_bounds__(256) void attn_out_kernel(
    const float* __restrict__ qkv, const float* __restrict__ sums,
    float* __restrict__ h) {
  int blk = blockIdx.x;
  int c = blk & (kNC - 1);
  int hh = (blk >> 5) & (kH - 1);
  int b = blk >> 8;
  int g0 = c * kCHUNK;
  __shared__ float qs[kCHUNK][36];
  __shared__ float ks[kCHUNK][36];
  __shared__ float vs[kCHUNK][36];
  __shared__ float Sf[kHD][kHD];
  __shared__ float ksum[kHD];
  __shared__ float dinv_s[kCHUNK];
  __shared__ float Amat[kCHUNK][68];
  int t = threadIdx.x;
  const float* base = qkv + (size_t)(b * kG + g0) * kQKVN + hh * kHD;
#pragma unroll
  for (int r = 0; r < 2; r++) {
    int e = t + r * 256;
    int i = e >> 3, j = (e & 7) * 4;
    *(float4*)&qs[i][j] = *(const float4*)&base[(size_t)i * kQKVN + j];
    *(float4*)&ks[i][j] = *(const float4*)&base[(size_t)i * kQKVN + 256 + j];
    *(float4*)&vs[i][j] = *(const float4*)&base[(size_t)i * kQKVN + 512 + j];
  }
  const float* sp = sums + (size_t)blk * kSUMSZ;
  *(float4*)&((float*)Sf)[t * 4] = *(const float4*)&sp[t * 4];
  if (t < 8) *(float4*)&ksum[t * 4] = *(const float4*)&sp[kHD * kHD + t * 4];
  __syncthreads();

  // Stage 1: Amat[i][j] = q_i . k_j, plus den_i folded in.
  // Thread: row i = t>>2, cols j = (t&3) + 4*jj  (4 consecutive rows per
  // instruction across the j-lanes -> distinct banks at stride 36).
  {
    int i = t >> 2, jb = t & 3;
    float qr[kHD];
#pragma unroll
    for (int m4 = 0; m4 < kHD / 4; m4++) {
      float4 qv = *(const float4*)&qs[i][m4 * 4];
      qr[m4 * 4 + 0] = qv.x; qr[m4 * 4 + 1] = qv.y;
      qr[m4 * 4 + 2] = qv.z; qr[m4 * 4 + 3] = qv.w;
    }
    float psum = 0.0f;
#pragma unroll
    for (int jj = 0; jj < 16; jj++) {
      int j = jb + jj * 4;
      float s = 0;
#pragma unroll
      for (int m4 = 0; m4 < kHD / 4; m4++) {
        float4 kv = *(const float4*)&ks[j][m4 * 4];
        s = fmaf(qr[m4 * 4 + 0], kv.x, s);
        s = fmaf(qr[m4 * 4 + 1], kv.y, s);
        s = fmaf(qr[m4 * 4 + 2], kv.z, s);
        s = fmaf(qr[m4 * 4 + 3], kv.w, s);
      }
      Amat[i][j] = s;                        // bank = (lane+4jj)%32: 2-way, free
      if (j <= i) psum += s;
    }
    psum += __shfl_xor(psum, 1);
    psum += __shfl_xor(psum, 2);
    if (jb == 0) {
      float dk = 0;
#pragma unroll
      for (int m = 0; m < kHD; m++) dk = fmaf(qr[m], ksum[m], dk);
      dinv_s[i] = 1.0f / (psum + dk + 1e-16f);
    }
  }
  __syncthreads();

  // Stage 2: num_i[n] = sum_{j<=i} A[i][j] v_j[n] + q_i . S ; h += num * dinv
  float* hbase = h + (size_t)(b * kG + g0) * kD + hh * kHD;
#pragma unroll
  for (int uu = 0; uu < 2; uu++) {
    int u = t + uu * 256;
    int i = u >> 3, n0 = (u & 7) * 4;
    float ax = 0, ay = 0, az = 0, aw = 0;
#pragma unroll
    for (int m = 0; m < kHD; m++) {
      float qm = qs[i][m];                   // bank (4i+m)%32: 8 distinct, free
      float4 s4 = *(const float4*)&Sf[m][n0];
      ax = fmaf(qm, s4.x, ax); ay = fmaf(qm, s4.y, ay);
      az = fmaf(qm, s4.z, az); aw = fmaf(qm, s4.w, aw);
    }
    for (int j = 0; j <= i; j++) {
      float w = Amat[i][j];                  // bank (4i+j)%32: 8 distinct, free
      float4 vv = *(const float4*)&vs[j][n0];
      ax = fmaf(w, vv.x, ax); ay = fmaf(w, vv.y, ay);
      az = fmaf(w, vv.z, az); aw = fmaf(w, vv.w, aw);
    }
    float dinv = dinv_s[i];
    float* hp = hbase + (size_t)i * kD + n0;
    float4 old = *(const float4*)hp;
    *(float4*)hp = make_float4(old.x + ax * dinv, old.y + ay * dinv,
                               old.z + az * dinv, old.w + aw * dinv);
  }
}

// ---------------------------------------------------------------------------
// out[row] = h[row,:] . Wo + bo. Wave-per-row, 4 rows/block.
__global__ __launch_bounds__(256) void final_kernel(
    const float* __restrict__ h, const float* __restrict__ Wo,
    const float* __restrict__ bo, float* __restrict__ out) {
  int w = threadIdx.x >> 6, lane = threadIdx.x & 63;
  size_t row = (size_t)blockIdx.x * 4 + w;
  float4 hv = *(const float4*)&h[row * kD + lane * 4];
  float4 wv = *(const float4*)&Wo[lane * 4];
  float s = hv.x * wv.x + hv.y * wv.y + hv.z * wv.z + hv.w * wv.w;
#pragma unroll
  for (int o = 32; o > 0; o >>= 1) s += __shfl_xor(s, o);
  if (lane == 0) out[row] = s + bo[0];
}

// ---------------------------------------------------------------------------
extern "C" void kernel_launch(void* const* d_in, const int* in_sizes, int n_in,
                              void* d_out, int out_size, void* d_ws, size_t ws_size,
                              hipStream_t stream) {
  const float* x    = (const float*)d_in[0];
  const float* ge   = (const float*)d_in[1];
  const float* Wq   = (const float*)d_in[2];
  const float* bq   = (const float*)d_in[3];
  const float* Wk   = (const float*)d_in[4];
  const float* bk   = (const float*)d_in[5];
  const float* Wv   = (const float*)d_in[6];
  const float* bv   = (const float*)d_in[7];
  const float* ln1g = (const float*)d_in[8];
  const float* ln1b = (const float*)d_in[9];
  const float* ln2g = (const float*)d_in[10];
  const float* ln2b = (const float*)d_in[11];
  const float* WU   = (const float*)d_in[12];
  const float* bU   = (const float*)d_in[13];
  const float* WV   = (const float*)d_in[14];
  const float* bV   = (const float*)d_in[15];
  const float* Wo   = (const float*)d_in[16];
  const float* bo   = (const float*)d_in[17];
  float* out = (float*)d_out;

  // Workspace layout (fp32 slot offsets; all 16B-aligned):
  float* ws = (float*)d_ws;
  float*          h       = ws;                        // 2,097,152 f32
  unsigned short* zb      = (unsigned short*)(ws + 2097152);   // 2,097,152 bf16
  float*          qkv     = ws + 3145728;              // 6,291,456 f32 [8192][768]
  unsigned short* u       = (unsigned short*)qkv;      // aliases qkv (disjoint phases)
  float*          sums    = ws + 9437184;              // 1,081,344 f32
  unsigned short* Wqkv_t  = (unsigned short*)(ws + 10518528);  // 786,432 bf16
  unsigned short* WU_t    = (unsigned short*)(ws + 10911744);  // 1,048,576 bf16
  unsigned short* WV_t    = (unsigned short*)(ws + 11436032);  // 1,048,576 bf16
  float*          bias_qkv= ws + 11960320;             // 3,072 f32

  dim3 blk256(256);
  convert_weights_kernel<<<kL * 704 + 12, blk256, 0, stream>>>(
      Wq, Wk, Wv, WU, WV, bq, bk, bv, Wqkv_t, WU_t, WV_t, bias_qkv);
  embed_kernel<<<kBG * kD / 256, blk256, 0, stream>>>(x, ge, h);
  for (int l = 0; l < kL; l++) {
    ln_kernel<<<kBG / 4, blk256, 0, stream>>>(h, ln1g + l * kD, ln1b + l * kD, zb);
    mfma_gemm<1, 64><<<dim3(kQKVN / 64, kBG / 128), blk256, 0, stream>>>(
        zb, Wqkv_t + (size_t)l * kQKVN * kD, bias_qkv + l * kQKVN, qkv, nullptr,
        kBG, kQKVN, kD);
    attn_sums_kernel<<<kB * kH * kNC, blk256, 0, stream>>>(qkv, sums);
    attn_scan_kernel<<<kB * kH * 5, blk256, 0, stream>>>(sums);
    attn_out_kernel<<<kB * kH * kNC, blk256, 0, stream>>>(qkv, sums, h);
    ln_kernel<<<kBG / 4, blk256, 0, stream>>>(h, ln2g + l * kD, ln2b + l * kD, zb);
    mfma_gemm<2, 128><<<dim3(kFFN / 128, kBG / 128), blk256, 0, stream>>>(
        zb, WU_t + (size_t)l * kFFN * kD, bU + l * kFFN, u, nullptr,
        kBG, kFFN, kD);
    mfma_gemm<3, 64><<<dim3(kD / 64, kBG / 128), blk256, 0, stream>>>(
        u, WV_t + (size_t)l * kD * kFFN, bV + l * kD, h, h,
        kBG, kD, kFFN);
  }
  final_kernel<<<kBG / 4, blk256, 0, stream>>>(h, Wo, bo, out);
}

// Round 4
// 425.911 us; speedup vs baseline: 3.2732x; 1.0546x over previous
//
#include <hip/hip_runtime.h>
#include <math.h>

// Problem constants
constexpr int kB = 4, kG = 2048, kD = 256, kH = 8, kHD = 32, kL = 4, kFFN = 1024;
constexpr int kBG = kB * kG;                  // 8192 tokens
constexpr int kCHUNK = 64;                    // linear-attn chunk length
constexpr int kNC = kG / kCHUNK;              // 32 chunks per sequence
constexpr int kSUMSZ = kHD * kHD + kHD;       // 1056 floats per chunk-state
constexpr int kQKVN = 3 * kD;                 // 768 fused QKV columns

typedef __bf16 bf16x8 __attribute__((ext_vector_type(8)));
typedef unsigned short ushort8 __attribute__((ext_vector_type(8)));
typedef float floatx4 __attribute__((ext_vector_type(4)));

__device__ __forceinline__ unsigned short f2bf(float f) {
  unsigned int u = __float_as_uint(f);
  u += 0x7fff + ((u >> 16) & 1);              // round-to-nearest-even
  return (unsigned short)(u >> 16);
}

__device__ __forceinline__ void load_lds_16(const void* g, void* l) {
  __builtin_amdgcn_global_load_lds((const __attribute__((address_space(1))) void*)g,
                                   (__attribute__((address_space(3))) void*)l,
                                   16, 0, 0);
}

// ---------------------------------------------------------------------------
// h[b,g,d] = gene_emb[g,d] + ree(x[b,g], d)
__global__ void embed_kernel(const float* __restrict__ x,
                             const float* __restrict__ ge,
                             float* __restrict__ h) {
  int idx = blockIdx.x * 256 + threadIdx.x;   // over kB*kG*kD = 2^21
  int d = idx & (kD - 1);
  int g = (idx >> 8) & (kG - 1);
  int b = idx >> 19;
  float xv = x[b * kG + g];
  int i = d & 127;
  float inv = expf(-(float)i * (4.6051701859880914f / 128.0f));  // 100^(-i/128)
  float f = xv * inv;
  float r = (d < 128) ? sinf(f) : cosf(f);
  if (xv == -10.0f) r = 0.0f;
  h[idx] = ge[g * kD + d] + r;
}

// ---------------------------------------------------------------------------
// Weight conversion: fp32 K-major -> bf16 N-major (transposed), plus QKV bias
// packing. One launch covers all layers.
__global__ void convert_weights_kernel(
    const float* __restrict__ Wq, const float* __restrict__ Wk,
    const float* __restrict__ Wv, const float* __restrict__ WU,
    const float* __restrict__ WV, const float* __restrict__ bq,
    const float* __restrict__ bk, const float* __restrict__ bv,
    unsigned short* __restrict__ Wqkv_t, unsigned short* __restrict__ WU_t,
    unsigned short* __restrict__ WV_t, float* __restrict__ bias_qkv) {
  int blk = blockIdx.x;
  if (blk >= kL * 704) {                       // bias-packing tail blocks
    int idx = (blk - kL * 704) * 256 + threadIdx.x;
    if (idx < kL * kQKVN) {
      int l = idx / kQKVN, n = idx % kQKVN;
      float v = (n < 256) ? bq[l * 256 + n]
              : (n < 512) ? bk[l * 256 + n - 256]
                          : bv[l * 256 + n - 512];
      bias_qkv[idx] = v;
    }
    return;
  }
  int l = blk / 704, id = blk % 704;
  const float* src;
  unsigned short* dst;
  int Ksrc, Nsrc, kt, nt;
  if (id < 192) {
    int m = id >> 6, tid = id & 63;
    src = (m == 0 ? Wq : m == 1 ? Wk : Wv) + (size_t)l * 256 * 256;
    dst = Wqkv_t + (size_t)l * kQKVN * 256 + (size_t)m * 256 * 256;
    Ksrc = 256; Nsrc = 256; kt = tid >> 3; nt = tid & 7;
  } else if (id < 448) {
    int tid = id - 192;
    src = WU + (size_t)l * 256 * 1024;
    dst = WU_t + (size_t)l * 1024 * 256;
    Ksrc = 256; Nsrc = 1024; kt = tid >> 5; nt = tid & 31;
  } else {
    int tid = id - 448;
    src = WV + (size_t)l * 1024 * 256;
    dst = WV_t + (size_t)l * 256 * 1024;
    Ksrc = 1024; Nsrc = 256; kt = tid >> 3; nt = tid & 7;
  }
  __shared__ float s[32][33];
  int tx = threadIdx.x & 31, ty = threadIdx.x >> 5;   // 32 x 8
#pragma unroll
  for (int r = 0; r < 4; r++)
    s[ty + r * 8][tx] = src[(size_t)(kt * 32 + ty + r * 8) * Nsrc + nt * 32 + tx];
  __syncthreads();
#pragma unroll
  for (int r = 0; r < 4; r++)
    dst[(size_t)(nt * 32 + ty + r * 8) * Ksrc + kt * 32 + tx] =
        f2bf(s[tx][ty + r * 8]);
}

// ---------------------------------------------------------------------------
// Row LayerNorm over D=256 -> bf16 output. Wave-per-row, 4 rows/block.
__global__ __launch_bounds__(256) void ln_kernel(
    const float* __restrict__ h, const float* __restrict__ gamma,
    const float* __restrict__ beta, unsigned short* __restrict__ z) {
  int w = threadIdx.x >> 6, lane = threadIdx.x & 63;
  size_t row = (size_t)blockIdx.x * 4 + w;
  float4 v = *(const float4*)&h[row * kD + lane * 4];
  float s = v.x + v.y + v.z + v.w;
  float sq = v.x * v.x + v.y * v.y + v.z * v.z + v.w * v.w;
#pragma unroll
  for (int o = 32; o > 0; o >>= 1) {
    s += __shfl_xor(s, o);
    sq += __shfl_xor(sq, o);
  }
  float mu = s * (1.0f / kD);
  float var = sq * (1.0f / kD) - mu * mu;
  float r = rsqrtf(var + 1e-5f);
  float4 g4 = *(const float4*)&gamma[lane * 4];
  float4 b4 = *(const float4*)&beta[lane * 4];
  float y0 = (v.x - mu) * r * g4.x + b4.x;
  float y1 = (v.y - mu) * r * g4.y + b4.y;
  float y2 = (v.z - mu) * r * g4.z + b4.z;
  float y3 = (v.w - mu) * r * g4.w + b4.w;
  unsigned int u0 = (unsigned int)f2bf(y0) | ((unsigned int)f2bf(y1) << 16);
  unsigned int u1 = (unsigned int)f2bf(y2) | ((unsigned int)f2bf(y3) << 16);
  uint2 uu; uu.x = u0; uu.y = u1;
  *(uint2*)&z[row * kD + lane * 4] = uu;
}

// ---------------------------------------------------------------------------
// bf16 MFMA GEMM, 64x64 tile, BK=32. Small tiles -> big grids (6-8 blocks/CU)
// so inter-block wave overlap hides the global_load_lds barrier drains
// (the 128-tile version sat at 2 blocks/CU, MfmaUtil 3%, latency-bound).
// A: M x K bf16 (row-major), Bt: N x K bf16 (row-major = W transposed).
// EPI: 1 = fused QKV (square cols < 512), fp32 out
//      2 = exact gelu, bf16 out
//      3 = residual add (Cres == C), fp32 out
template <int EPI>
__global__ __launch_bounds__(256) void mfma_gemm(
    const unsigned short* __restrict__ A, const unsigned short* __restrict__ Bt,
    const float* __restrict__ bias, void* __restrict__ Cout,
    const float* __restrict__ Cres, int M, int N, int K) {
  __shared__ unsigned short As[64 * 32];      // 4 KB
  __shared__ unsigned short Bs[64 * 32];      // 4 KB
  const int t = threadIdx.x;
  const int w = t >> 6, lane = t & 63;
  const int bm = blockIdx.y * 64, bn = blockIdx.x * 64;
  const int wm = (w >> 1) * 32, wn = (w & 1) * 32;

  // Staging: wave w fills rows w*16..w*16+15 of both tiles (1 KB per load).
  const int srow = lane >> 2;            // 0..15 within chunk
  const int skof = (lane & 3) * 8;       // k element offset of 16B piece
  const unsigned short* ap = A + (size_t)(bm + w * 16 + srow) * K + skof;
  const unsigned short* bp = Bt + (size_t)(bn + w * 16 + srow) * K + skof;
  unsigned short* asd = &As[w * 512];
  unsigned short* bsd = &Bs[w * 512];

  floatx4 acc[2][2];
#pragma unroll
  for (int i = 0; i < 2; i++)
#pragma unroll
    for (int j = 0; j < 2; j++) acc[i][j] = (floatx4){0.f, 0.f, 0.f, 0.f};

  const int lm = lane & 15, lq = lane >> 4;
  const unsigned short* afp = &As[(wm + lm) * 32 + lq * 8];
  const unsigned short* bfp = &Bs[(wn + lm) * 32 + lq * 8];

  for (int k0 = 0; k0 < K; k0 += 32) {
    load_lds_16(ap + k0, asd);
    load_lds_16(bp + k0, bsd);
    __syncthreads();
    bf16x8 af[2], bfr[2];
#pragma unroll
    for (int i = 0; i < 2; i++)
      af[i] = __builtin_bit_cast(bf16x8,
          *reinterpret_cast<const ushort8*>(afp + i * 16 * 32));
#pragma unroll
    for (int j = 0; j < 2; j++)
      bfr[j] = __builtin_bit_cast(bf16x8,
          *reinterpret_cast<const ushort8*>(bfp + j * 16 * 32));
#pragma unroll
    for (int i = 0; i < 2; i++)
#pragma unroll
      for (int j = 0; j < 2; j++)
        acc[i][j] = __builtin_amdgcn_mfma_f32_16x16x32_bf16(af[i], bfr[j],
                                                            acc[i][j], 0, 0, 0);
    __syncthreads();
  }

  // Epilogue. C/D layout: col = lane&15, row = (lane>>4)*4 + reg.
  const int r0 = bm + wm + lq * 4;
  const int c0 = bn + wn + lm;
#pragma unroll
  for (int j = 0; j < 2; j++) {
    int col = c0 + j * 16;
    float bv = bias[col];
#pragma unroll
    for (int i = 0; i < 2; i++) {
      int rowb = r0 + i * 16;
#pragma unroll
      for (int r = 0; r < 4; r++) {
        int row = rowb + r;
        float v = acc[i][j][r] + bv;
        size_t idx = (size_t)row * N + col;
        if (EPI == 1) {
          ((float*)Cout)[idx] = (col < 512) ? v * v : v;
        } else if (EPI == 2) {
          float g = 0.5f * v * (1.0f + erff(v * 0.70710678118654752f));
          ((unsigned short*)Cout)[idx] = f2bf(g);
        } else {
          ((float*)Cout)[idx] = Cres[idx] + v;
        }
      }
    }
  }
}

// ---------------------------------------------------------------------------
// Per-chunk summaries from fused qkv buffer (row stride 768).
__global__ __launch_bounds__(256) void attn_sums_kernel(
    const float* __restrict__ qkv, float* __restrict__ sums) {
  int blk = blockIdx.x;              // b*(H*NC) + h*NC + c
  int c = blk & (kNC - 1);
  int hh = (blk >> 5) & (kH - 1);
  int b = blk >> 8;
  int g0 = c * kCHUNK;
  __shared__ float ks[kCHUNK][kHD];
  __shared__ float vs[kCHUNK][kHD];
  const float* kbase = qkv + (size_t)(b * kG + g0) * kQKVN + 256 + hh * kHD;
  const float* vbase = qkv + (size_t)(b * kG + g0) * kQKVN + 512 + hh * kHD;
#pragma unroll
  for (int r = 0; r < 2; r++) {
    int e = threadIdx.x + r * 256;
    int i = e >> 3, j = (e & 7) * 4;
    *(float4*)&ks[i][j] = *(const float4*)&kbase[(size_t)i * kQKVN + j];
    *(float4*)&vs[i][j] = *(const float4*)&vbase[(size_t)i * kQKVN + j];
  }
  __syncthreads();
  int m = threadIdx.x >> 3, n0 = (threadIdx.x & 7) * 4;
  float a0 = 0, a1 = 0, a2 = 0, a3 = 0;
  for (int i = 0; i < kCHUNK; i++) {
    float km = ks[i][m];
    float4 v4 = *(const float4*)&vs[i][n0];
    a0 = fmaf(km, v4.x, a0); a1 = fmaf(km, v4.y, a1);
    a2 = fmaf(km, v4.z, a2); a3 = fmaf(km, v4.w, a3);
  }
  float* outp = sums + (size_t)blk * kSUMSZ;
  *(float4*)&outp[m * kHD + n0] = make_float4(a0, a1, a2, a3);
  if (threadIdx.x < kHD) {
    float s = 0;
    for (int i = 0; i < kCHUNK; i++) s += ks[i][threadIdx.x];
    outp[kHD * kHD + threadIdx.x] = s;
  }
}

// ---------------------------------------------------------------------------
// Exclusive prefix scan over chunks. Batched loads (independent, pipelined),
// register prefix, batched stores. grid = kB*kH*5, block = 256.
__global__ void attn_scan_kernel(float* __restrict__ sums) {
  int bh = blockIdx.x / 5, part = blockIdx.x % 5;
  int e = part * 256 + threadIdx.x;
  if (e >= kSUMSZ) return;
  float* base = sums + (size_t)bh * kNC * kSUMSZ + e;
  float v[kNC];
#pragma unroll
  for (int c = 0; c < kNC; c++) v[c] = base[(size_t)c * kSUMSZ];
  float run = 0;
#pragma unroll
  for (int c = 0; c < kNC; c++) {
    float tv = v[c];
    base[(size_t)c * kSUMSZ] = run;
    run += tv;
  }
}

// ---------------------------------------------------------------------------
// Per-chunk output: o = (QK^T masked)·V + Q·S_prev, normalized; h += o
// Conflict-free LDS layout: q/k/v stride 36, Amat stride 68; den folded into
// the A-build stage (reuses q registers, shfl reduce over the 4 j-lanes).
__global__ __launch_bounds__(256) void attn_out_kernel(
    const float* __restrict__ qkv, const float* __restrict__ sums,
    float* __restrict__ h) {
  int blk = blockIdx.x;
  int c = blk & (kNC - 1);
  int hh = (blk >> 5) & (kH - 1);
  int b = blk >> 8;
  int g0 = c * kCHUNK;
  __shared__ float qs[kCHUNK][36];
  __shared__ float ks[kCHUNK][36];
  __shared__ float vs[kCHUNK][36];
  __shared__ float Sf[kHD][kHD];
  __shared__ float ksum[kHD];
  __shared__ float dinv_s[kCHUNK];
  __shared__ float Amat[kCHUNK][68];
  int t = threadIdx.x;
  const float* base = qkv + (size_t)(b * kG + g0) * kQKVN + hh * kHD;
#pragma unroll
  for (int r = 0; r < 2; r++) {
    int e = t + r * 256;
    int i = e >> 3, j = (e & 7) * 4;
    *(float4*)&qs[i][j] = *(const float4*)&base[(size_t)i * kQKVN + j];
    *(float4*)&ks[i][j] = *(const float4*)&base[(size_t)i * kQKVN + 256 + j];
    *(float4*)&vs[i][j] = *(const float4*)&base[(size_t)i * kQKVN + 512 + j];
  }
  const float* sp = sums + (size_t)blk * kSUMSZ;
  *(float4*)&((float*)Sf)[t * 4] = *(const float4*)&sp[t * 4];
  if (t < 8) *(float4*)&ksum[t * 4] = *(const float4*)&sp[kHD * kHD + t * 4];
  __syncthreads();

  // Stage 1: Amat[i][j] = q_i . k_j, plus den_i folded in.
  {
    int i = t >> 2, jb = t & 3;
    float qr[kHD];
#pragma unroll
    for (int m4 = 0; m4 < kHD / 4; m4++) {
      float4 qv = *(const float4*)&qs[i][m4 * 4];
      qr[m4 * 4 + 0] = qv.x; qr[m4 * 4 + 1] = qv.y;
      qr[m4 * 4 + 2] = qv.z; qr[m4 * 4 + 3] = qv.w;
    }
    float psum = 0.0f;
#pragma unroll
    for (int jj = 0; jj < 16; jj++) {
      int j = jb + jj * 4;
      float s = 0;
#pragma unroll
      for (int m4 = 0; m4 < kHD / 4; m4++) {
        float4 kv = *(const float4*)&ks[j][m4 * 4];
        s = fmaf(qr[m4 * 4 + 0], kv.x, s);
        s = fmaf(qr[m4 * 4 + 1], kv.y, s);
        s = fmaf(qr[m4 * 4 + 2], kv.z, s);
        s = fmaf(qr[m4 * 4 + 3], kv.w, s);
      }
      Amat[i][j] = s;
      if (j <= i) psum += s;
    }
    psum += __shfl_xor(psum, 1);
    psum += __shfl_xor(psum, 2);
    if (jb == 0) {
      float dk = 0;
#pragma unroll
      for (int m = 0; m < kHD; m++) dk = fmaf(qr[m], ksum[m], dk);
      dinv_s[i] = 1.0f / (psum + dk + 1e-16f);
    }
  }
  __syncthreads();

  // Stage 2: num_i[n] = sum_{j<=i} A[i][j] v_j[n] + q_i . S ; h += num * dinv
  float* hbase = h + (size_t)(b * kG + g0) * kD + hh * kHD;
#pragma unroll
  for (int uu = 0; uu < 2; uu++) {
    int u = t + uu * 256;
    int i = u >> 3, n0 = (u & 7) * 4;
    float ax = 0, ay = 0, az = 0, aw = 0;
#pragma unroll
    for (int m = 0; m < kHD; m++) {
      float qm = qs[i][m];
      float4 s4 = *(const float4*)&Sf[m][n0];
      ax = fmaf(qm, s4.x, ax); ay = fmaf(qm, s4.y, ay);
      az = fmaf(qm, s4.z, az); aw = fmaf(qm, s4.w, aw);
    }
    for (int j = 0; j <= i; j++) {
      float w = Amat[i][j];
      float4 vv = *(const float4*)&vs[j][n0];
      ax = fmaf(w, vv.x, ax); ay = fmaf(w, vv.y, ay);
      az = fmaf(w, vv.z, az); aw = fmaf(w, vv.w, aw);
    }
    float dinv = dinv_s[i];
    float* hp = hbase + (size_t)i * kD + n0;
    float4 old = *(const float4*)hp;
    *(float4*)hp = make_float4(old.x + ax * dinv, old.y + ay * dinv,
                               old.z + az * dinv, old.w + aw * dinv);
  }
}

// ---------------------------------------------------------------------------
// out[row] = h[row,:] . Wo + bo. Wave-per-row, 4 rows/block.
__global__ __launch_bounds__(256) void final_kernel(
    const float* __restrict__ h, const float* __restrict__ Wo,
    const float* __restrict__ bo, float* __restrict__ out) {
  int w = threadIdx.x >> 6, lane = threadIdx.x & 63;
  size_t row = (size_t)blockIdx.x * 4 + w;
  float4 hv = *(const float4*)&h[row * kD + lane * 4];
  float4 wv = *(const float4*)&Wo[lane * 4];
  float s = hv.x * wv.x + hv.y * wv.y + hv.z * wv.z + hv.w * wv.w;
#pragma unroll
  for (int o = 32; o > 0; o >>= 1) s += __shfl_xor(s, o);
  if (lane == 0) out[row] = s + bo[0];
}

// ---------------------------------------------------------------------------
extern "C" void kernel_launch(void* const* d_in, const int* in_sizes, int n_in,
                              void* d_out, int out_size, void* d_ws, size_t ws_size,
                              hipStream_t stream) {
  const float* x    = (const float*)d_in[0];
  const float* ge   = (const float*)d_in[1];
  const float* Wq   = (const float*)d_in[2];
  const float* bq   = (const float*)d_in[3];
  const float* Wk   = (const float*)d_in[4];
  const float* bk   = (const float*)d_in[5];
  const float* Wv   = (const float*)d_in[6];
  const float* bv   = (const float*)d_in[7];
  const float* ln1g = (const float*)d_in[8];
  const float* ln1b = (const float*)d_in[9];
  const float* ln2g = (const float*)d_in[10];
  const float* ln2b = (const float*)d_in[11];
  const float* WU   = (const float*)d_in[12];
  const float* bU   = (const float*)d_in[13];
  const float* WV   = (const float*)d_in[14];
  const float* bV   = (const float*)d_in[15];
  const float* Wo   = (const float*)d_in[16];
  const float* bo   = (const float*)d_in[17];
  float* out = (float*)d_out;

  // Workspace layout (fp32 slot offsets; all 16B-aligned):
  float* ws = (float*)d_ws;
  float*          h       = ws;                        // 2,097,152 f32
  unsigned short* zb      = (unsigned short*)(ws + 2097152);   // 2,097,152 bf16
  float*          qkv     = ws + 3145728;              // 6,291,456 f32 [8192][768]
  unsigned short* u       = (unsigned short*)qkv;      // aliases qkv (disjoint phases)
  float*          sums    = ws + 9437184;              // 1,081,344 f32
  unsigned short* Wqkv_t  = (unsigned short*)(ws + 10518528);  // 786,432 bf16
  unsigned short* WU_t    = (unsigned short*)(ws + 10911744);  // 1,048,576 bf16
  unsigned short* WV_t    = (unsigned short*)(ws + 11436032);  // 1,048,576 bf16
  float*          bias_qkv= ws + 11960320;             // 3,072 f32

  dim3 blk256(256);
  convert_weights_kernel<<<kL * 704 + 12, blk256, 0, stream>>>(
      Wq, Wk, Wv, WU, WV, bq, bk, bv, Wqkv_t, WU_t, WV_t, bias_qkv);
  embed_kernel<<<kBG * kD / 256, blk256, 0, stream>>>(x, ge, h);
  for (int l = 0; l < kL; l++) {
    ln_kernel<<<kBG / 4, blk256, 0, stream>>>(h, ln1g + l * kD, ln1b + l * kD, zb);
    mfma_gemm<1><<<dim3(kQKVN / 64, kBG / 64), blk256, 0, stream>>>(
        zb, Wqkv_t + (size_t)l * kQKVN * kD, bias_qkv + l * kQKVN, qkv, nullptr,
        kBG, kQKVN, kD);
    attn_sums_kernel<<<kB * kH * kNC, blk256, 0, stream>>>(qkv, sums);
    attn_scan_kernel<<<kB * kH * 5, blk256, 0, stream>>>(sums);
    attn_out_kernel<<<kB * kH * kNC, blk256, 0, stream>>>(qkv, sums, h);
    ln_kernel<<<kBG / 4, blk256, 0, stream>>>(h, ln2g + l * kD, ln2b + l * kD, zb);
    mfma_gemm<2><<<dim3(kFFN / 64, kBG / 64), blk256, 0, stream>>>(
        zb, WU_t + (size_t)l * kFFN * kD, bU + l * kFFN, u, nullptr,
        kBG, kFFN, kD);
    mfma_gemm<3><<<dim3(kD / 64, kBG / 64), blk256, 0, stream>>>(
        u, WV_t + (size_t)l * kD * kFFN, bV + l * kD, h, h,
        kBG, kD, kFFN);
  }
  final_kernel<<<kBG / 4, blk256, 0, stream>>>(h, Wo, bo, out);
}